// Round 4
// baseline (1508.311 us; speedup 1.0000x reference)
//
#include <hip/hip_runtime.h>
#include <hip/hip_bf16.h>
#include <utility>

#define CIC 8   // conv input-channel chunk

// ---------------- patch embed (conv4x4 s4) + ln2d64 fused; one wave per pixel
__global__ void k_patch_embed_ln(const float* __restrict__ E0, const float* __restrict__ w,
                                 const float* __restrict__ b, const float* __restrict__ g,
                                 const float* __restrict__ lb, float* __restrict__ out) {
  int p = blockIdx.x;
  int c = threadIdx.x;  // 64
  int oh = p >> 6, ow = p & 63;
  const float* src = E0 + (oh * 4) * 256 + ow * 4;
  const float* wc = w + c * 16;
  float acc = b[c];
#pragma unroll
  for (int i = 0; i < 4; i++)
#pragma unroll
    for (int j = 0; j < 4; j++) acc += src[i * 256 + j] * wc[i * 4 + j];
  float s = acc, s2 = acc * acc;
#pragma unroll
  for (int m = 32; m >= 1; m >>= 1) {
    s += __shfl_xor(s, m, 64);
    s2 += __shfl_xor(s2, m, 64);
  }
  float mu = s * (1.f / 64.f);
  float var = s2 * (1.f / 64.f) - mu * mu;
  float rstd = rsqrtf(var + 1e-6f);
  out[c * 4096 + p] = (acc - mu) * rstd * g[c] + lb[c];
}

// ---------------- ln2d over C=64 channels (one wave per pixel)
__global__ void k_ln2d64(const float* __restrict__ x, const float* __restrict__ g,
                         const float* __restrict__ b, float* __restrict__ y, int HW) {
  int p = blockIdx.x;
  int c = threadIdx.x;
  float v = x[c * HW + p];
  float s = v, s2 = v * v;
#pragma unroll
  for (int m = 32; m >= 1; m >>= 1) {
    s += __shfl_xor(s, m, 64);
    s2 += __shfl_xor(s2, m, 64);
  }
  float mu = s * (1.f / 64.f);
  float var = s2 * (1.f / 64.f) - mu * mu;
  float rstd = rsqrtf(var + 1e-6f);
  y[c * HW + p] = (v - mu) * rstd * g[c] + b[c];
}

// ---------------- fused ln2d(C=64) + input projection (64 -> 256), split xc/z
__global__ void k_lnproj(const float* __restrict__ x, const float* __restrict__ g,
                         const float* __restrict__ b, const float* __restrict__ w,
                         float* __restrict__ xc, float* __restrict__ z, int HW) {
  int p = blockIdx.x;
  int t = threadIdx.x;  // 256 threads
  __shared__ float hsh[64];
  if (t < 64) {
    float v = x[t * HW + p];
    float s = v, s2 = v * v;
#pragma unroll
    for (int m = 32; m >= 1; m >>= 1) {
      s += __shfl_xor(s, m, 64);
      s2 += __shfl_xor(s2, m, 64);
    }
    float mu = s * (1.f / 64.f);
    float var = s2 * (1.f / 64.f) - mu * mu;
    float rstd = rsqrtf(var + 1e-6f);
    hsh[t] = (v - mu) * rstd * g[t] + b[t];
  }
  __syncthreads();
  float acc = 0.f;
  const float* wp = w + t;  // w[c*256 + t]
#pragma unroll
  for (int c = 0; c < 64; c++) acc += hsh[c] * wp[c * 256];
  if (t < 128)
    xc[(size_t)p * 128 + t] = acc;
  else
    z[(size_t)p * 128 + (t - 128)] = acc;
}

// ---------------- depthwise conv 3x3 pad 1 + silu; pixel-major [L][128]
__global__ void k_dwconv(const float* __restrict__ xc, const float* __restrict__ w,
                         const float* __restrict__ b, float* __restrict__ out, int H, int lgH) {
  int HW = H * H;
  int idx = blockIdx.x * blockDim.x + threadIdx.x;
  if (idx >= 128 * HW) return;
  int p = idx >> 7;
  int d = idx & 127;
  int ph = p >> lgH, pw = p & (H - 1);
  const float* wp = w + d * 9;
  float acc = b[d];
#pragma unroll
  for (int i = 0; i < 3; i++) {
    int ih = ph + i - 1;
    if (ih < 0 || ih >= H) continue;
#pragma unroll
    for (int j = 0; j < 3; j++) {
      int iw = pw + j - 1;
      if (iw < 0 || iw >= H) continue;
      acc += xc[(size_t)(ih * H + iw) * 128 + d] * wp[i * 3 + j];
    }
  }
  out[(size_t)p * 128 + d] = acc / (1.f + __expf(-acc));
}

// ---------------- x-projection + delta=softplus(...)
__global__ void k_xproj(const float* __restrict__ xcs, const float* __restrict__ xpw,
                        const float* __restrict__ dtw, const float* __restrict__ dtb,
                        float* __restrict__ delta, float* __restrict__ Bs,
                        float* __restrict__ Cs, int H, int lgH) {
  int L = H * H;
  int l = blockIdx.x;
  int k = blockIdx.y;
  int t = threadIdx.x;  // 256
  int lm = (k & 2) ? (L - 1 - l) : l;
  int idx = (k & 1) ? ((lm & (H - 1)) * H + (lm >> lgH)) : lm;
  __shared__ float xs[128];
  __shared__ float part[36][4];
  __shared__ float r4[4];
  if (t < 128) xs[t] = xcs[(size_t)idx * 128 + t];
  __syncthreads();
  if (t < 144) {
    int r = t >> 2, q = t & 3;
    const float* wr = xpw + (k * 36 + r) * 128 + q * 32;
    const float* xp = xs + q * 32;
    float acc = 0.f;
#pragma unroll
    for (int c = 0; c < 32; c++) acc += xp[c] * wr[c];
    part[r][q] = acc;
  }
  __syncthreads();
  if (t < 36) {
    float acc = part[t][0] + part[t][1] + part[t][2] + part[t][3];
    if (t < 4)
      r4[t] = acc;
    else if (t < 20)
      Bs[((size_t)k * L + l) * 16 + (t - 4)] = acc;
    else
      Cs[((size_t)k * L + l) * 16 + (t - 20)] = acc;
  }
  __syncthreads();
  if (t < 128) {
    float dt = dtb[k * 128 + t];
    const float* wd = dtw + (k * 128 + t) * 4;
    dt += r4[0] * wd[0] + r4[1] * wd[1] + r4[2] * wd[2] + r4[3] * wd[3];
    float sp = fmaxf(dt, 0.f) + log1pf(__expf(-fabsf(dt)));
    delta[((size_t)k * L + l) * 128 + t] = sp;
  }
}

// ---------------- scan phase A
__global__ void k_scanA(const float* __restrict__ xcs, const float* __restrict__ delta,
                        const float* __restrict__ Bs, const float* __restrict__ A_log,
                        float* __restrict__ hloc, float* __restrict__ pA, int H, int lgH,
                        int nc, int cs) {
  int L = H * H;
  int c = blockIdx.x;
  int k = blockIdx.y;
  int d = threadIdx.x;  // 128
  float A[16], h[16];
#pragma unroll
  for (int n = 0; n < 16; n++) {
    A[n] = -expf(A_log[(k * 128 + d) * 16 + n]);
    h[n] = 0.f;
  }
  float sumdt = 0.f;
  int l0 = c * cs;
  for (int l = l0; l < l0 + cs; l++) {
    int lm = (k & 2) ? (L - 1 - l) : l;
    int idx = (k & 1) ? ((lm & (H - 1)) * H + (lm >> lgH)) : lm;
    float u = xcs[(size_t)idx * 128 + d];
    float dt = delta[((size_t)k * L + l) * 128 + d];
    float du = dt * u;
    sumdt += dt;
    const float4* bp = (const float4*)(Bs + ((size_t)k * L + l) * 16);
    float4 B0 = bp[0], B1 = bp[1], B2 = bp[2], B3 = bp[3];
    float Bv[16] = {B0.x, B0.y, B0.z, B0.w, B1.x, B1.y, B1.z, B1.w,
                    B2.x, B2.y, B2.z, B2.w, B3.x, B3.y, B3.z, B3.w};
#pragma unroll
    for (int n = 0; n < 16; n++) h[n] = __expf(dt * A[n]) * h[n] + Bv[n] * du;
  }
  size_t base = (((size_t)(k * 128 + d)) * nc + c) * 16;
#pragma unroll
  for (int n = 0; n < 16; n++) {
    hloc[base + n] = h[n];
    pA[base + n] = __expf(A[n] * sumdt);
  }
}

// ---------------- scan phase B: 8192 independent (k,d,n) recurrences
__global__ void k_scanB(const float* __restrict__ hloc, const float* __restrict__ pA,
                        float* __restrict__ hinit, int nc) {
  int tid = blockIdx.x * blockDim.x + threadIdx.x;  // 8192 total
  int k = tid >> 11;
  int d = (tid >> 4) & 127;
  int n = tid & 15;
  size_t rb = ((size_t)(k * 128 + d)) * nc * 16 + n;
  float h = 0.f;
  for (int c = 0; c < nc; c++) {
    size_t a = rb + (size_t)c * 16;
    hinit[a] = h;
    h = pA[a] * h + hloc[a];
  }
}

// ---------------- scan phase C
__global__ void k_scanC(const float* __restrict__ xcs, const float* __restrict__ delta,
                        const float* __restrict__ Bs, const float* __restrict__ Cs,
                        const float* __restrict__ A_log, const float* __restrict__ Dp,
                        const float* __restrict__ hinit, float* __restrict__ ys, int H,
                        int lgH, int nc, int cs) {
  int L = H * H;
  int c = blockIdx.x;
  int k = blockIdx.y;
  int d = threadIdx.x;
  float A[16], h[16];
  size_t base = (((size_t)(k * 128 + d)) * nc + c) * 16;
#pragma unroll
  for (int n = 0; n < 16; n++) {
    A[n] = -expf(A_log[(k * 128 + d) * 16 + n]);
    h[n] = hinit[base + n];
  }
  float Dv = Dp[k * 128 + d];
  int l0 = c * cs;
  for (int l = l0; l < l0 + cs; l++) {
    int lm = (k & 2) ? (L - 1 - l) : l;
    int idx = (k & 1) ? ((lm & (H - 1)) * H + (lm >> lgH)) : lm;
    float u = xcs[(size_t)idx * 128 + d];
    float dt = delta[((size_t)k * L + l) * 128 + d];
    float du = dt * u;
    const float4* bp = (const float4*)(Bs + ((size_t)k * L + l) * 16);
    float4 B0 = bp[0], B1 = bp[1], B2 = bp[2], B3 = bp[3];
    float Bv[16] = {B0.x, B0.y, B0.z, B0.w, B1.x, B1.y, B1.z, B1.w,
                    B2.x, B2.y, B2.z, B2.w, B3.x, B3.y, B3.z, B3.w};
    const float4* cp = (const float4*)(Cs + ((size_t)k * L + l) * 16);
    float4 C0 = cp[0], C1 = cp[1], C2 = cp[2], C3 = cp[3];
    float Cv[16] = {C0.x, C0.y, C0.z, C0.w, C1.x, C1.y, C1.z, C1.w,
                    C2.x, C2.y, C2.z, C2.w, C3.x, C3.y, C3.z, C3.w};
    float y = 0.f;
#pragma unroll
    for (int n = 0; n < 16; n++) {
      h[n] = __expf(dt * A[n]) * h[n] + Bv[n] * du;
      y += h[n] * Cv[n];
    }
    ys[((size_t)k * L + l) * 128 + d] = y + Dv * u;
  }
}

// ---------------- fused scan A+B+C for small L (grid=4 dirs, 1024 threads)
__global__ void __launch_bounds__(1024) k_scan_fused(
    const float* __restrict__ xcs, const float* __restrict__ delta,
    const float* __restrict__ Bs, const float* __restrict__ Cs,
    const float* __restrict__ A_log, const float* __restrict__ Dp,
    float* __restrict__ hloc, float* __restrict__ pA, float* __restrict__ hinit,
    float* __restrict__ ys, int H, int lgH, int nc) {
  const int cs = 8;
  int L = H * H;
  int k = blockIdx.x;
  // phase A
  for (int item = threadIdx.x; item < nc * 128; item += 1024) {
    int c = item >> 7, d = item & 127;
    float A[16], h[16];
#pragma unroll
    for (int n = 0; n < 16; n++) {
      A[n] = -expf(A_log[(k * 128 + d) * 16 + n]);
      h[n] = 0.f;
    }
    float sumdt = 0.f;
    int l0 = c * cs;
    for (int l = l0; l < l0 + cs; l++) {
      int lm = (k & 2) ? (L - 1 - l) : l;
      int idx = (k & 1) ? ((lm & (H - 1)) * H + (lm >> lgH)) : lm;
      float u = xcs[(size_t)idx * 128 + d];
      float dt = delta[((size_t)k * L + l) * 128 + d];
      float du = dt * u;
      sumdt += dt;
      const float4* bp = (const float4*)(Bs + ((size_t)k * L + l) * 16);
      float4 B0 = bp[0], B1 = bp[1], B2 = bp[2], B3 = bp[3];
      float Bv[16] = {B0.x, B0.y, B0.z, B0.w, B1.x, B1.y, B1.z, B1.w,
                      B2.x, B2.y, B2.z, B2.w, B3.x, B3.y, B3.z, B3.w};
#pragma unroll
      for (int n = 0; n < 16; n++) h[n] = __expf(dt * A[n]) * h[n] + Bv[n] * du;
    }
    size_t base = (((size_t)(k * 128 + d)) * nc + c) * 16;
#pragma unroll
    for (int n = 0; n < 16; n++) {
      hloc[base + n] = h[n];
      pA[base + n] = __expf(A[n] * sumdt);
    }
  }
  __syncthreads();
  // phase B
  for (int item = threadIdx.x; item < 2048; item += 1024) {
    int d = item >> 4, n = item & 15;
    size_t rb = ((size_t)(k * 128 + d)) * nc * 16 + n;
    float h = 0.f;
    for (int c = 0; c < nc; c++) {
      size_t a = rb + (size_t)c * 16;
      hinit[a] = h;
      h = pA[a] * h + hloc[a];
    }
  }
  __syncthreads();
  // phase C
  for (int item = threadIdx.x; item < nc * 128; item += 1024) {
    int c = item >> 7, d = item & 127;
    float A[16], h[16];
    size_t base = (((size_t)(k * 128 + d)) * nc + c) * 16;
#pragma unroll
    for (int n = 0; n < 16; n++) {
      A[n] = -expf(A_log[(k * 128 + d) * 16 + n]);
      h[n] = hinit[base + n];
    }
    float Dv = Dp[k * 128 + d];
    int l0 = c * cs;
    for (int l = l0; l < l0 + cs; l++) {
      int lm = (k & 2) ? (L - 1 - l) : l;
      int idx = (k & 1) ? ((lm & (H - 1)) * H + (lm >> lgH)) : lm;
      float u = xcs[(size_t)idx * 128 + d];
      float dt = delta[((size_t)k * L + l) * 128 + d];
      float du = dt * u;
      const float4* bp = (const float4*)(Bs + ((size_t)k * L + l) * 16);
      float4 B0 = bp[0], B1 = bp[1], B2 = bp[2], B3 = bp[3];
      float Bv[16] = {B0.x, B0.y, B0.z, B0.w, B1.x, B1.y, B1.z, B1.w,
                      B2.x, B2.y, B2.z, B2.w, B3.x, B3.y, B3.z, B3.w};
      const float4* cp = (const float4*)(Cs + ((size_t)k * L + l) * 16);
      float4 C0 = cp[0], C1 = cp[1], C2 = cp[2], C3 = cp[3];
      float Cv[16] = {C0.x, C0.y, C0.z, C0.w, C1.x, C1.y, C1.z, C1.w,
                      C2.x, C2.y, C2.z, C2.w, C3.x, C3.y, C3.z, C3.w};
      float y = 0.f;
#pragma unroll
      for (int n = 0; n < 16; n++) {
        h[n] = __expf(dt * A[n]) * h[n] + Bv[n] * du;
        y += h[n] * Cv[n];
      }
      ys[((size_t)k * L + l) * 128 + d] = y + Dv * u;
    }
  }
}

// ---------------- combine (plain): 4 dirs + LN128 + gate + out proj + residual
__global__ void k_combine(const float* __restrict__ ys, const float* __restrict__ z,
                          const float* __restrict__ xin, const float* __restrict__ ong,
                          const float* __restrict__ onb, const float* __restrict__ outw,
                          float* __restrict__ xout, int H, int lgH) {
  int L = H * H;
  int p = blockIdx.x;
  int d = threadIdx.x;  // 128
  int ph = p >> lgH, pw = p & (H - 1);
  int l1 = pw * H + ph;
  float yv = ys[((size_t)0 * L + p) * 128 + d] + ys[((size_t)1 * L + l1) * 128 + d] +
             ys[((size_t)2 * L + (L - 1 - p)) * 128 + d] +
             ys[((size_t)3 * L + (L - 1 - l1)) * 128 + d];
  float s = yv, s2 = yv * yv;
#pragma unroll
  for (int m = 32; m >= 1; m >>= 1) {
    s += __shfl_xor(s, m, 64);
    s2 += __shfl_xor(s2, m, 64);
  }
  __shared__ float ws1[2], ws2[2];
  int wid = d >> 6;
  if ((d & 63) == 0) {
    ws1[wid] = s;
    ws2[wid] = s2;
  }
  __syncthreads();
  float tot = ws1[0] + ws1[1], tot2 = ws2[0] + ws2[1];
  float mu = tot * (1.f / 128.f);
  float var = tot2 * (1.f / 128.f) - mu * mu;
  float rstd = rsqrtf(var + 1e-6f);
  float zt = z[(size_t)p * 128 + d];
  float yt = ((yv - mu) * rstd * ong[d] + onb[d]) * (zt / (1.f + __expf(-zt)));
  __shared__ float ysm[128];
  ysm[d] = yt;
  __syncthreads();
  if (d < 64) {
    float acc = xin[(size_t)d * L + p];
#pragma unroll
    for (int q = 0; q < 128; q++) acc += ysm[q] * outw[q * 64 + d];
    xout[(size_t)d * L + p] = acc;
  }
}

// ---------------- combine + next-block LN64 + in-proj fused (256 threads/pixel)
__global__ void k_combine_lnproj(const float* __restrict__ ys, const float* __restrict__ z,
                                 const float* __restrict__ xin, const float* __restrict__ ong,
                                 const float* __restrict__ onb, const float* __restrict__ outw,
                                 const float* __restrict__ g2, const float* __restrict__ b2,
                                 const float* __restrict__ w2, float* __restrict__ xout,
                                 float* __restrict__ xc, float* __restrict__ zout, int H,
                                 int lgH) {
  int L = H * H;
  int p = blockIdx.x;
  int t = threadIdx.x;  // 256
  __shared__ float ysm[128], hnsh[64];
  __shared__ float ws1[2], ws2[2];
  float yv = 0.f;
  if (t < 128) {
    int ph = p >> lgH, pw = p & (H - 1);
    int l1 = pw * H + ph;
    yv = ys[((size_t)0 * L + p) * 128 + t] + ys[((size_t)1 * L + l1) * 128 + t] +
         ys[((size_t)2 * L + (L - 1 - p)) * 128 + t] +
         ys[((size_t)3 * L + (L - 1 - l1)) * 128 + t];
    float s = yv, s2 = yv * yv;
#pragma unroll
    for (int m = 32; m >= 1; m >>= 1) {
      s += __shfl_xor(s, m, 64);
      s2 += __shfl_xor(s2, m, 64);
    }
    if ((t & 63) == 0) {
      ws1[t >> 6] = s;
      ws2[t >> 6] = s2;
    }
  }
  __syncthreads();
  if (t < 128) {
    float tot = ws1[0] + ws1[1], tot2 = ws2[0] + ws2[1];
    float mu = tot * (1.f / 128.f);
    float var = tot2 * (1.f / 128.f) - mu * mu;
    float rstd = rsqrtf(var + 1e-6f);
    float zt = z[(size_t)p * 128 + t];
    ysm[t] = ((yv - mu) * rstd * ong[t] + onb[t]) * (zt / (1.f + __expf(-zt)));
  }
  __syncthreads();
  if (t < 64) {
    float acc = xin[(size_t)t * L + p];
#pragma unroll
    for (int q = 0; q < 128; q++) acc += ysm[q] * outw[q * 64 + t];
    xout[(size_t)t * L + p] = acc;  // residual x for next combine
    float s = acc, s2 = acc * acc;
#pragma unroll
    for (int m = 32; m >= 1; m >>= 1) {
      s += __shfl_xor(s, m, 64);
      s2 += __shfl_xor(s2, m, 64);
    }
    float mu = s * (1.f / 64.f);
    float var = s2 * (1.f / 64.f) - mu * mu;
    float rstd = rsqrtf(var + 1e-6f);
    hnsh[t] = (acc - mu) * rstd * g2[t] + b2[t];
  }
  __syncthreads();
  float a2 = 0.f;
  const float* wp = w2 + t;
#pragma unroll
  for (int c = 0; c < 64; c++) a2 += hnsh[c] * wp[c * 256];
  if (t < 128)
    xc[(size_t)p * 128 + t] = a2;
  else
    zout[(size_t)p * 128 + (t - 128)] = a2;
}

// ---------------- naive per-output conv3x3 64->64 (stride 1 or 2, silu, skip)
__global__ void k_conv_naive(const float* __restrict__ x, const float* __restrict__ w,
                             const float* __restrict__ b, const float* __restrict__ skip,
                             float* __restrict__ out, int Hin, int Hout, int stride,
                             int do_silu) {
  int idx = blockIdx.x * blockDim.x + threadIdx.x;
  int HWo = Hout * Hout;
  if (idx >= 64 * HWo) return;
  int co = idx / HWo;
  int p = idx - co * HWo;
  int oh = p / Hout, ow = p - (p / Hout) * Hout;
  float acc = b[co];
  const float* wb = w + co * 64 * 9;
  for (int ci = 0; ci < 64; ci++) {
    const float* xb = x + (size_t)ci * Hin * Hin;
    const float* wc = wb + ci * 9;
#pragma unroll
    for (int i = 0; i < 3; i++) {
      int ih = oh * stride + i - 1;
      if (ih < 0 || ih >= Hin) continue;
#pragma unroll
      for (int j = 0; j < 3; j++) {
        int iw = ow * stride + j - 1;
        if (iw < 0 || iw >= Hin) continue;
        acc += xb[ih * Hin + iw] * wc[i * 3 + j];
      }
    }
  }
  if (do_silu) acc = acc / (1.f + __expf(-acc));
  if (skip) acc += skip[idx];
  out[idx] = acc;
}

// ---------------- final: fused (x4 bilinear resize) + conv3x3 + silu
// grid (16,16,4): 16x16 px tile, 16 co per block. 256 thr: 2x2 px x 4 co.
__global__ void __launch_bounds__(256) k_conv16_up(const float* __restrict__ x,
                                                   const float* __restrict__ w,
                                                   const float* __restrict__ b,
                                                   float* __restrict__ out) {
  __shared__ __align__(16) float xsh[CIC][18][18];
  __shared__ __align__(16) float wsh[CIC][16][12];
  int t = threadIdx.x;
  int q = t & 63, cog = t >> 6;  // wave id == cog
  int qx = q & 7, qy = q >> 3;
  int ox = blockIdx.x * 16, oy = blockIdx.y * 16;
  int z16 = blockIdx.z * 16;
  float acc[4][4];
#pragma unroll
  for (int pp = 0; pp < 4; pp++)
#pragma unroll
    for (int i = 0; i < 4; i++) acc[pp][i] = 0.f;
  for (int cb = 0; cb < 64; cb += CIC) {
    // stage input tile with inline x4 bilinear upsample (zero outside canvas)
    for (int i = t; i < CIC * 324; i += 256) {
      int ci = i / 324;
      int r = i - ci * 324;
      int iy = r / 18, ix = r - (r / 18) * 18;
      int gy = oy + iy - 1, gx = ox + ix - 1;
      float v = 0.f;
      if (gy >= 0 && gy < 256 && gx >= 0 && gx < 256) {
        float sh = gy * 0.25f - 0.375f;
        float sw = gx * 0.25f - 0.375f;
        int h0 = (int)floorf(sh);
        float fh = sh - h0;
        int w0 = (int)floorf(sw);
        float fw = sw - w0;
        int h0c = max(h0, 0), h1c = min(h0 + 1, 63);
        int w0c = max(w0, 0), w1c = min(w0 + 1, 63);
        const float* xb = x + (size_t)(cb + ci) * 4096;
        v = (1.f - fh) * ((1.f - fw) * xb[h0c * 64 + w0c] + fw * xb[h0c * 64 + w1c]) +
            fh * ((1.f - fw) * xb[h1c * 64 + w0c] + fw * xb[h1c * 64 + w1c]);
      }
      xsh[ci][iy][ix] = v;
    }
    for (int i = t; i < CIC * 144; i += 256) {
      int ci = i / 144;
      int r = i - ci * 144;
      int col = r / 9, tap = r - (r / 9) * 9;
      wsh[ci][col][tap] = w[(size_t)(z16 + col) * 576 + (cb + ci) * 9 + tap];
    }
    __syncthreads();
#pragma unroll
    for (int ci = 0; ci < CIC; ci++) {
      float xv[4][4];
#pragma unroll
      for (int r = 0; r < 4; r++) {
        float2 a = *(const float2*)&xsh[ci][2 * qy + r][2 * qx];
        float2 bq = *(const float2*)&xsh[ci][2 * qy + r][2 * qx + 2];
        xv[r][0] = a.x;
        xv[r][1] = a.y;
        xv[r][2] = bq.x;
        xv[r][3] = bq.y;
      }
#pragma unroll
      for (int i = 0; i < 4; i++) {
        int col = cog * 4 + i;
        float4 w0 = *(const float4*)&wsh[ci][col][0];
        float4 w1 = *(const float4*)&wsh[ci][col][4];
        float w8 = wsh[ci][col][8];
#pragma unroll
        for (int dy = 0; dy < 2; dy++)
#pragma unroll
          for (int dx = 0; dx < 2; dx++) {
            acc[dy * 2 + dx][i] += xv[dy + 0][dx + 0] * w0.x + xv[dy + 0][dx + 1] * w0.y +
                                   xv[dy + 0][dx + 2] * w0.z + xv[dy + 1][dx + 0] * w0.w +
                                   xv[dy + 1][dx + 1] * w1.x + xv[dy + 1][dx + 2] * w1.y +
                                   xv[dy + 2][dx + 0] * w1.z + xv[dy + 2][dx + 1] * w1.w +
                                   xv[dy + 2][dx + 2] * w8;
          }
      }
    }
    __syncthreads();
  }
#pragma unroll
  for (int dy = 0; dy < 2; dy++)
#pragma unroll
    for (int dx = 0; dx < 2; dx++) {
      int gy = oy + 2 * qy + dy, gx = ox + 2 * qx + dx;
#pragma unroll
      for (int i = 0; i < 4; i++) {
        int co = z16 + cog * 4 + i;
        float a = acc[dy * 2 + dx][i] + b[co];
        a = a / (1.f + __expf(-a));
        out[(size_t)co * 65536 + gy * 256 + gx] = a;
      }
    }
}

// ---------------- bilinear resize (half-pixel centers, edge clamp)
__global__ void k_resize(const float* __restrict__ x, float* __restrict__ out, int Hin,
                         int Win, int Hout, int Wout, float inv_scale) {
  int idx = blockIdx.x * blockDim.x + threadIdx.x;
  int HWo = Hout * Wout;
  if (idx >= 64 * HWo) return;
  int c = idx / HWo;
  int p = idx - c * HWo;
  int oh = p / Wout, ow = p - (p / Wout) * Wout;
  float sh = (oh + 0.5f) * inv_scale - 0.5f;
  float sw = (ow + 0.5f) * inv_scale - 0.5f;
  int h0 = (int)floorf(sh);
  float fh = sh - h0;
  int w0 = (int)floorf(sw);
  float fw = sw - w0;
  int h0c = min(max(h0, 0), Hin - 1), h1c = min(max(h0 + 1, 0), Hin - 1);
  int w0c = min(max(w0, 0), Win - 1), w1c = min(max(w0 + 1, 0), Win - 1);
  const float* xb = x + (size_t)c * Hin * Win;
  float v = (1.f - fh) * ((1.f - fw) * xb[h0c * Win + w0c] + fw * xb[h0c * Win + w1c]) +
            fh * ((1.f - fw) * xb[h1c * Win + w0c] + fw * xb[h1c * Win + w1c]);
  out[idx] = v;
}

extern "C" void kernel_launch(void* const* d_in, const int* in_sizes, int n_in, void* d_out,
                              int out_size, void* d_ws, size_t ws_size, hipStream_t stream) {
  const float* E0 = (const float*)d_in[0];
  const float* pe_w = (const float*)d_in[1];
  const float* pe_b = (const float*)d_in[2];
  const float* pe_lg = (const float*)d_in[3];
  const float* pe_lb = (const float*)d_in[4];
  const float* ln_g = (const float*)d_in[5];
  const float* ln_b = (const float*)d_in[6];
  const float* in_w = (const float*)d_in[7];
  const float* cv_w = (const float*)d_in[8];
  const float* cv_b = (const float*)d_in[9];
  const float* xp_w = (const float*)d_in[10];
  const float* dt_w = (const float*)d_in[11];
  const float* dt_b = (const float*)d_in[12];
  const float* A_log = (const float*)d_in[13];
  const float* Dp = (const float*)d_in[14];
  const float* on_g = (const float*)d_in[15];
  const float* on_b = (const float*)d_in[16];
  const float* out_pw = (const float*)d_in[17];
  const float* dn_w = (const float*)d_in[18];
  const float* dn_b = (const float*)d_in[19];
  const float* dn_g = (const float*)d_in[20];
  const float* dn_lb = (const float*)d_in[21];
  const float* up_w = (const float*)d_in[22];
  const float* up_b = (const float*)d_in[23];
  const float* oc_w = (const float*)d_in[24];
  const float* oc_b = (const float*)d_in[25];

  float* ws = (float*)d_ws;
  size_t off = 0;
  auto alloc = [&](size_t n) {
    float* p = ws + off;
    off += n;
    return p;
  };
  float* xA = alloc(64 * 4096);
  float* xB = alloc(64 * 4096);
  float* xc = alloc(128 * 4096);
  float* zb = alloc(128 * 4096);
  float* xcs = alloc(128 * 4096);
  float* dlt = alloc((size_t)4 * 128 * 4096);
  float* Bsb = alloc(4 * 16 * 4096);
  float* Csb = alloc(4 * 16 * 4096);
  float* ysb = alloc((size_t)4 * 128 * 4096);
  float* hloc = alloc((size_t)4 * 128 * 256 * 16);
  float* pAb = alloc((size_t)4 * 128 * 256 * 16);
  float* hin = alloc((size_t)4 * 128 * 256 * 16);
  float* sk0 = alloc(64 * 4096);
  float* sk1 = alloc(64 * 1024);
  float* sk2 = alloc(64 * 256);
  float* sk3 = alloc(64 * 64);
  float* tmpR = alloc((size_t)64 * 4096);

  k_patch_embed_ln<<<4096, 64, 0, stream>>>(E0, pe_w, pe_b, pe_lg, pe_lb, xB);
  float* x = xB;
  float* xalt = xA;

  int Hs[4] = {64, 32, 16, 8};
  int lgHs[4] = {6, 5, 4, 3};
  int CSs[4] = {16, 8, 8, 8};
  float* skips[4] = {sk0, sk1, sk2, sk3};
  int cur = 0;

  // runs dwconv..scan..; combine handled by caller variant
  auto vss_core = [&](int H, int lgH, int cs, bool fused_scan) {
    int L = H * H;
    int nc = L / cs;
    k_dwconv<<<(128 * L + 255) / 256, 256, 0, stream>>>(xc, cv_w + (size_t)cur * 128 * 9,
                                                        cv_b + cur * 128, xcs, H, lgH);
    dim3 gx(L, 4);
    k_xproj<<<gx, 256, 0, stream>>>(xcs, xp_w + (size_t)cur * 4 * 36 * 128,
                                    dt_w + (size_t)cur * 4 * 128 * 4, dt_b + cur * 4 * 128,
                                    dlt, Bsb, Csb, H, lgH);
    const float* Al = A_log + (size_t)cur * 4 * 128 * 16;
    const float* Dv = Dp + cur * 4 * 128;
    if (fused_scan) {
      k_scan_fused<<<4, 1024, 0, stream>>>(xcs, dlt, Bsb, Csb, Al, Dv, hloc, pAb, hin, ysb,
                                           H, lgH, nc);
    } else {
      dim3 ga(nc, 4);
      k_scanA<<<ga, 128, 0, stream>>>(xcs, dlt, Bsb, Al, hloc, pAb, H, lgH, nc, cs);
      k_scanB<<<32, 256, 0, stream>>>(hloc, pAb, hin, nc);
      k_scanC<<<ga, 128, 0, stream>>>(xcs, dlt, Bsb, Csb, Al, Dv, hin, ysb, H, lgH, nc, cs);
    }
  };

  for (int i = 0; i < 4; i++) {
    int H = Hs[i], lgH = lgHs[i];
    int L = H * H;
    bool fs = (i >= 2);
    // VSS block 1
    k_lnproj<<<L, 256, 0, stream>>>(x, ln_g + cur * 64, ln_b + cur * 64,
                                    in_w + (size_t)cur * 64 * 256, xc, zb, L);
    vss_core(H, lgH, CSs[i], fs);
    k_combine_lnproj<<<L, 256, 0, stream>>>(
        ysb, zb, x, on_g + cur * 128, on_b + cur * 128, out_pw + (size_t)cur * 128 * 64,
        ln_g + (cur + 1) * 64, ln_b + (cur + 1) * 64, in_w + (size_t)(cur + 1) * 64 * 256,
        xalt, xc, zb, H, lgH);
    std::swap(x, xalt);
    cur++;
    // VSS block 2 (xc/zb already produced)
    vss_core(H, lgH, CSs[i], fs);
    k_combine<<<L, 128, 0, stream>>>(ysb, zb, x, on_g + cur * 128, on_b + cur * 128,
                                     out_pw + (size_t)cur * 128 * 64, xalt, H, lgH);
    std::swap(x, xalt);
    cur++;

    hipMemcpyAsync(skips[i], x, (size_t)64 * L * sizeof(float), hipMemcpyDeviceToDevice,
                   stream);
    if (i < 3) {
      int Ho = H / 2;
      k_conv_naive<<<(64 * Ho * Ho + 255) / 256, 256, 0, stream>>>(
          x, dn_w + (size_t)i * 64 * 64 * 9, dn_b + i * 64, nullptr, xalt, H, Ho, 2, 0);
      k_ln2d64<<<Ho * Ho, 64, 0, stream>>>(xalt, dn_g + i * 64, dn_lb + i * 64, x, Ho * Ho);
    }
  }

  // up path: x at 8x8
  for (int i = 0; i < 3; i++) {
    int Hin = 8 << i, Ho = Hin * 2;
    k_resize<<<(64 * Ho * Ho + 255) / 256, 256, 0, stream>>>(x, tmpR, Hin, Hin, Ho, Ho, 0.5f);
    k_conv_naive<<<(64 * Ho * Ho + 255) / 256, 256, 0, stream>>>(
        tmpR, up_w + (size_t)i * 64 * 64 * 9, up_b + i * 64, skips[2 - i], xalt, Ho, Ho, 1, 1);
    std::swap(x, xalt);
  }

  // final: x at 64x64 -> fused (resize x4 + conv3x3 + silu) -> d_out
  dim3 gf(16, 16, 4);
  k_conv16_up<<<gf, 256, 0, stream>>>(x, oc_w, oc_b, (float*)d_out);
}

// Round 5
// 1352.492 us; speedup vs baseline: 1.1152x; 1.1152x over previous
//
#include <hip/hip_runtime.h>
#include <hip/hip_bf16.h>
#include <utility>

// ---------------- patch embed (conv4x4 s4) + ln2d64 fused; one wave per pixel
__global__ void k_patch_embed_ln(const float* __restrict__ E0, const float* __restrict__ w,
                                 const float* __restrict__ b, const float* __restrict__ g,
                                 const float* __restrict__ lb, float* __restrict__ out) {
  int p = blockIdx.x;
  int c = threadIdx.x;  // 64
  int oh = p >> 6, ow = p & 63;
  const float* src = E0 + (oh * 4) * 256 + ow * 4;
  const float* wc = w + c * 16;
  float acc = b[c];
#pragma unroll
  for (int i = 0; i < 4; i++)
#pragma unroll
    for (int j = 0; j < 4; j++) acc += src[i * 256 + j] * wc[i * 4 + j];
  float s = acc, s2 = acc * acc;
#pragma unroll
  for (int m = 32; m >= 1; m >>= 1) {
    s += __shfl_xor(s, m, 64);
    s2 += __shfl_xor(s2, m, 64);
  }
  float mu = s * (1.f / 64.f);
  float var = s2 * (1.f / 64.f) - mu * mu;
  float rstd = rsqrtf(var + 1e-6f);
  out[c * 4096 + p] = (acc - mu) * rstd * g[c] + lb[c];
}

// ---------------- ln2d over C=64 channels (one wave per pixel)
__global__ void k_ln2d64(const float* __restrict__ x, const float* __restrict__ g,
                         const float* __restrict__ b, float* __restrict__ y, int HW) {
  int p = blockIdx.x;
  int c = threadIdx.x;
  float v = x[c * HW + p];
  float s = v, s2 = v * v;
#pragma unroll
  for (int m = 32; m >= 1; m >>= 1) {
    s += __shfl_xor(s, m, 64);
    s2 += __shfl_xor(s2, m, 64);
  }
  float mu = s * (1.f / 64.f);
  float var = s2 * (1.f / 64.f) - mu * mu;
  float rstd = rsqrtf(var + 1e-6f);
  y[c * HW + p] = (v - mu) * rstd * g[c] + b[c];
}

// ---------------- fused ln2d(C=64) + input projection (64 -> 256), split xc/z
__global__ void k_lnproj(const float* __restrict__ x, const float* __restrict__ g,
                         const float* __restrict__ b, const float* __restrict__ w,
                         float* __restrict__ xc, float* __restrict__ z, int HW) {
  int p = blockIdx.x;
  int t = threadIdx.x;  // 256 threads
  __shared__ float hsh[64];
  if (t < 64) {
    float v = x[t * HW + p];
    float s = v, s2 = v * v;
#pragma unroll
    for (int m = 32; m >= 1; m >>= 1) {
      s += __shfl_xor(s, m, 64);
      s2 += __shfl_xor(s2, m, 64);
    }
    float mu = s * (1.f / 64.f);
    float var = s2 * (1.f / 64.f) - mu * mu;
    float rstd = rsqrtf(var + 1e-6f);
    hsh[t] = (v - mu) * rstd * g[t] + b[t];
  }
  __syncthreads();
  float acc = 0.f;
  const float* wp = w + t;  // w[c*256 + t]
#pragma unroll
  for (int c = 0; c < 64; c++) acc += hsh[c] * wp[c * 256];
  if (t < 128)
    xc[(size_t)p * 128 + t] = acc;
  else
    z[(size_t)p * 128 + (t - 128)] = acc;
}

// ---------------- depthwise conv 3x3 pad 1 + silu; pixel-major [L][128]
__global__ void k_dwconv(const float* __restrict__ xc, const float* __restrict__ w,
                         const float* __restrict__ b, float* __restrict__ out, int H, int lgH) {
  int HW = H * H;
  int idx = blockIdx.x * blockDim.x + threadIdx.x;
  if (idx >= 128 * HW) return;
  int p = idx >> 7;
  int d = idx & 127;
  int ph = p >> lgH, pw = p & (H - 1);
  const float* wp = w + d * 9;
  float acc = b[d];
#pragma unroll
  for (int i = 0; i < 3; i++) {
    int ih = ph + i - 1;
    if (ih < 0 || ih >= H) continue;
#pragma unroll
    for (int j = 0; j < 3; j++) {
      int iw = pw + j - 1;
      if (iw < 0 || iw >= H) continue;
      acc += xc[(size_t)(ih * H + iw) * 128 + d] * wp[i * 3 + j];
    }
  }
  out[(size_t)p * 128 + d] = acc / (1.f + __expf(-acc));
}

// ---------------- x-projection + delta=softplus(...)
__global__ void k_xproj(const float* __restrict__ xcs, const float* __restrict__ xpw,
                        const float* __restrict__ dtw, const float* __restrict__ dtb,
                        float* __restrict__ delta, float* __restrict__ Bs,
                        float* __restrict__ Cs, int H, int lgH) {
  int L = H * H;
  int l = blockIdx.x;
  int k = blockIdx.y;
  int t = threadIdx.x;  // 256
  int lm = (k & 2) ? (L - 1 - l) : l;
  int idx = (k & 1) ? ((lm & (H - 1)) * H + (lm >> lgH)) : lm;
  __shared__ float xs[128];
  __shared__ float part[36][4];
  __shared__ float r4[4];
  if (t < 128) xs[t] = xcs[(size_t)idx * 128 + t];
  __syncthreads();
  if (t < 144) {
    int r = t >> 2, q = t & 3;
    const float* wr = xpw + (k * 36 + r) * 128 + q * 32;
    const float* xp = xs + q * 32;
    float acc = 0.f;
#pragma unroll
    for (int c = 0; c < 32; c++) acc += xp[c] * wr[c];
    part[r][q] = acc;
  }
  __syncthreads();
  if (t < 36) {
    float acc = part[t][0] + part[t][1] + part[t][2] + part[t][3];
    if (t < 4)
      r4[t] = acc;
    else if (t < 20)
      Bs[((size_t)k * L + l) * 16 + (t - 4)] = acc;
    else
      Cs[((size_t)k * L + l) * 16 + (t - 20)] = acc;
  }
  __syncthreads();
  if (t < 128) {
    float dt = dtb[k * 128 + t];
    const float* wd = dtw + (k * 128 + t) * 4;
    dt += r4[0] * wd[0] + r4[1] * wd[1] + r4[2] * wd[2] + r4[3] * wd[3];
    float sp = fmaxf(dt, 0.f) + log1pf(__expf(-fabsf(dt)));
    delta[((size_t)k * L + l) * 128 + t] = sp;
  }
}

// ---------------- scan phase A: per-chunk local scan (init 0) + chunk decay
__global__ void k_scanA(const float* __restrict__ xcs, const float* __restrict__ delta,
                        const float* __restrict__ Bs, const float* __restrict__ A_log,
                        float* __restrict__ hloc, float* __restrict__ pA, int H, int lgH,
                        int nc, int cs) {
  int L = H * H;
  int c = blockIdx.x;
  int k = blockIdx.y;
  int d = threadIdx.x;  // 128
  float A[16], h[16];
#pragma unroll
  for (int n = 0; n < 16; n++) {
    A[n] = -expf(A_log[(k * 128 + d) * 16 + n]);
    h[n] = 0.f;
  }
  float sumdt = 0.f;
  int l0 = c * cs;
  for (int l = l0; l < l0 + cs; l++) {
    int lm = (k & 2) ? (L - 1 - l) : l;
    int idx = (k & 1) ? ((lm & (H - 1)) * H + (lm >> lgH)) : lm;
    float u = xcs[(size_t)idx * 128 + d];
    float dt = delta[((size_t)k * L + l) * 128 + d];
    float du = dt * u;
    sumdt += dt;
    const float4* bp = (const float4*)(Bs + ((size_t)k * L + l) * 16);
    float4 B0 = bp[0], B1 = bp[1], B2 = bp[2], B3 = bp[3];
    float Bv[16] = {B0.x, B0.y, B0.z, B0.w, B1.x, B1.y, B1.z, B1.w,
                    B2.x, B2.y, B2.z, B2.w, B3.x, B3.y, B3.z, B3.w};
#pragma unroll
    for (int n = 0; n < 16; n++) h[n] = __expf(dt * A[n]) * h[n] + Bv[n] * du;
  }
  size_t base = (((size_t)(k * 128 + d)) * nc + c) * 16;
#pragma unroll
  for (int n = 0; n < 16; n++) {
    hloc[base + n] = h[n];
    pA[base + n] = __expf(A[n] * sumdt);
  }
}

// ---------------- scan phase B: 8192 independent (k,d,n) recurrences
__global__ void k_scanB(const float* __restrict__ hloc, const float* __restrict__ pA,
                        float* __restrict__ hinit, int nc) {
  int tid = blockIdx.x * blockDim.x + threadIdx.x;  // 8192 total
  int k = tid >> 11;
  int d = (tid >> 4) & 127;
  int n = tid & 15;
  size_t rb = ((size_t)(k * 128 + d)) * nc * 16 + n;
  float h = 0.f;
  for (int c = 0; c < nc; c++) {
    size_t a = rb + (size_t)c * 16;
    hinit[a] = h;
    h = pA[a] * h + hloc[a];
  }
}

// ---------------- scan phase C: rescan with correct init, emit y; ys: [k][L][128]
__global__ void k_scanC(const float* __restrict__ xcs, const float* __restrict__ delta,
                        const float* __restrict__ Bs, const float* __restrict__ Cs,
                        const float* __restrict__ A_log, const float* __restrict__ Dp,
                        const float* __restrict__ hinit, float* __restrict__ ys, int H,
                        int lgH, int nc, int cs) {
  int L = H * H;
  int c = blockIdx.x;
  int k = blockIdx.y;
  int d = threadIdx.x;
  float A[16], h[16];
  size_t base = (((size_t)(k * 128 + d)) * nc + c) * 16;
#pragma unroll
  for (int n = 0; n < 16; n++) {
    A[n] = -expf(A_log[(k * 128 + d) * 16 + n]);
    h[n] = hinit[base + n];
  }
  float Dv = Dp[k * 128 + d];
  int l0 = c * cs;
  for (int l = l0; l < l0 + cs; l++) {
    int lm = (k & 2) ? (L - 1 - l) : l;
    int idx = (k & 1) ? ((lm & (H - 1)) * H + (lm >> lgH)) : lm;
    float u = xcs[(size_t)idx * 128 + d];
    float dt = delta[((size_t)k * L + l) * 128 + d];
    float du = dt * u;
    const float4* bp = (const float4*)(Bs + ((size_t)k * L + l) * 16);
    float4 B0 = bp[0], B1 = bp[1], B2 = bp[2], B3 = bp[3];
    float Bv[16] = {B0.x, B0.y, B0.z, B0.w, B1.x, B1.y, B1.z, B1.w,
                    B2.x, B2.y, B2.z, B2.w, B3.x, B3.y, B3.z, B3.w};
    const float4* cp = (const float4*)(Cs + ((size_t)k * L + l) * 16);
    float4 C0 = cp[0], C1 = cp[1], C2 = cp[2], C3 = cp[3];
    float Cv[16] = {C0.x, C0.y, C0.z, C0.w, C1.x, C1.y, C1.z, C1.w,
                    C2.x, C2.y, C2.z, C2.w, C3.x, C3.y, C3.z, C3.w};
    float y = 0.f;
#pragma unroll
    for (int n = 0; n < 16; n++) {
      h[n] = __expf(dt * A[n]) * h[n] + Bv[n] * du;
      y += h[n] * Cv[n];
    }
    ys[((size_t)k * L + l) * 128 + d] = y + Dv * u;
  }
}

// ---------------- combine (plain): 4 dirs + LN128 + gate + out proj + residual
__global__ void k_combine(const float* __restrict__ ys, const float* __restrict__ z,
                          const float* __restrict__ xin, const float* __restrict__ ong,
                          const float* __restrict__ onb, const float* __restrict__ outw,
                          float* __restrict__ xout, int H, int lgH) {
  int L = H * H;
  int p = blockIdx.x;
  int d = threadIdx.x;  // 128
  int ph = p >> lgH, pw = p & (H - 1);
  int l1 = pw * H + ph;
  float yv = ys[((size_t)0 * L + p) * 128 + d] + ys[((size_t)1 * L + l1) * 128 + d] +
             ys[((size_t)2 * L + (L - 1 - p)) * 128 + d] +
             ys[((size_t)3 * L + (L - 1 - l1)) * 128 + d];
  float s = yv, s2 = yv * yv;
#pragma unroll
  for (int m = 32; m >= 1; m >>= 1) {
    s += __shfl_xor(s, m, 64);
    s2 += __shfl_xor(s2, m, 64);
  }
  __shared__ float ws1[2], ws2[2];
  int wid = d >> 6;
  if ((d & 63) == 0) {
    ws1[wid] = s;
    ws2[wid] = s2;
  }
  __syncthreads();
  float tot = ws1[0] + ws1[1], tot2 = ws2[0] + ws2[1];
  float mu = tot * (1.f / 128.f);
  float var = tot2 * (1.f / 128.f) - mu * mu;
  float rstd = rsqrtf(var + 1e-6f);
  float zt = z[(size_t)p * 128 + d];
  float yt = ((yv - mu) * rstd * ong[d] + onb[d]) * (zt / (1.f + __expf(-zt)));
  __shared__ float ysm[128];
  ysm[d] = yt;
  __syncthreads();
  if (d < 64) {
    float acc = xin[(size_t)d * L + p];
#pragma unroll
    for (int q = 0; q < 128; q++) acc += ysm[q] * outw[q * 64 + d];
    xout[(size_t)d * L + p] = acc;
  }
}

// ---------------- combine + next-block LN64 + in-proj fused (256 threads/pixel)
__global__ void k_combine_lnproj(const float* __restrict__ ys, const float* __restrict__ z,
                                 const float* __restrict__ xin, const float* __restrict__ ong,
                                 const float* __restrict__ onb, const float* __restrict__ outw,
                                 const float* __restrict__ g2, const float* __restrict__ b2,
                                 const float* __restrict__ w2, float* __restrict__ xout,
                                 float* __restrict__ xc, float* __restrict__ zout, int H,
                                 int lgH) {
  int L = H * H;
  int p = blockIdx.x;
  int t = threadIdx.x;  // 256
  __shared__ float ysm[128], hnsh[64];
  __shared__ float ws1[2], ws2[2];
  float yv = 0.f;
  if (t < 128) {
    int ph = p >> lgH, pw = p & (H - 1);
    int l1 = pw * H + ph;
    yv = ys[((size_t)0 * L + p) * 128 + t] + ys[((size_t)1 * L + l1) * 128 + t] +
         ys[((size_t)2 * L + (L - 1 - p)) * 128 + t] +
         ys[((size_t)3 * L + (L - 1 - l1)) * 128 + t];
    float s = yv, s2 = yv * yv;
#pragma unroll
    for (int m = 32; m >= 1; m >>= 1) {
      s += __shfl_xor(s, m, 64);
      s2 += __shfl_xor(s2, m, 64);
    }
    if ((t & 63) == 0) {
      ws1[t >> 6] = s;
      ws2[t >> 6] = s2;
    }
  }
  __syncthreads();
  if (t < 128) {
    float tot = ws1[0] + ws1[1], tot2 = ws2[0] + ws2[1];
    float mu = tot * (1.f / 128.f);
    float var = tot2 * (1.f / 128.f) - mu * mu;
    float rstd = rsqrtf(var + 1e-6f);
    float zt = z[(size_t)p * 128 + t];
    ysm[t] = ((yv - mu) * rstd * ong[t] + onb[t]) * (zt / (1.f + __expf(-zt)));
  }
  __syncthreads();
  if (t < 64) {
    float acc = xin[(size_t)t * L + p];
#pragma unroll
    for (int q = 0; q < 128; q++) acc += ysm[q] * outw[q * 64 + t];
    xout[(size_t)t * L + p] = acc;  // residual x for next combine
    float s = acc, s2 = acc * acc;
#pragma unroll
    for (int m = 32; m >= 1; m >>= 1) {
      s += __shfl_xor(s, m, 64);
      s2 += __shfl_xor(s2, m, 64);
    }
    float mu = s * (1.f / 64.f);
    float var = s2 * (1.f / 64.f) - mu * mu;
    float rstd = rsqrtf(var + 1e-6f);
    hnsh[t] = (acc - mu) * rstd * g2[t] + b2[t];
  }
  __syncthreads();
  float a2 = 0.f;
  const float* wp = w2 + t;
#pragma unroll
  for (int c = 0; c < 64; c++) a2 += hnsh[c] * wp[c * 256];
  if (t < 128)
    xc[(size_t)p * 128 + t] = a2;
  else
    zout[(size_t)p * 128 + (t - 128)] = a2;
}

// ---------------- naive per-output conv3x3 64->64 (stride 1 or 2, silu, skip)
__global__ void k_conv_naive(const float* __restrict__ x, const float* __restrict__ w,
                             const float* __restrict__ b, const float* __restrict__ skip,
                             float* __restrict__ out, int Hin, int Hout, int stride,
                             int do_silu) {
  int idx = blockIdx.x * blockDim.x + threadIdx.x;
  int HWo = Hout * Hout;
  if (idx >= 64 * HWo) return;
  int co = idx / HWo;
  int p = idx - co * HWo;
  int oh = p / Hout, ow = p - (p / Hout) * Hout;
  float acc = b[co];
  const float* wb = w + co * 64 * 9;
  for (int ci = 0; ci < 64; ci++) {
    const float* xb = x + (size_t)ci * Hin * Hin;
    const float* wc = wb + ci * 9;
#pragma unroll
    for (int i = 0; i < 3; i++) {
      int ih = oh * stride + i - 1;
      if (ih < 0 || ih >= Hin) continue;
#pragma unroll
      for (int j = 0; j < 3; j++) {
        int iw = ow * stride + j - 1;
        if (iw < 0 || iw >= Hin) continue;
        acc += xb[ih * Hin + iw] * wc[i * 3 + j];
      }
    }
  }
  if (do_silu) acc = acc / (1.f + __expf(-acc));
  if (skip) acc += skip[idx];
  out[idx] = acc;
}

// ---------------- final: fused (x4 bilinear resize) + conv3x3 + silu
// grid (16,16,4): 16x16 px tile, 16 co per block. 256 thr: 2x2 px x 4 co.
// CIC=16 (two staging phases), xsh padded to 20 words/row (2-way max conflict).
__global__ void __launch_bounds__(256) k_conv16_up(const float* __restrict__ x,
                                                   const float* __restrict__ w,
                                                   const float* __restrict__ b,
                                                   float* __restrict__ out) {
  __shared__ __align__(16) float xsh[16][18][20];
  __shared__ __align__(16) float wsh[16][16][12];
  int t = threadIdx.x;
  int q = t & 63, cog = t >> 6;  // wave id == cog -> broadcast weight reads
  int qx = q & 7, qy = q >> 3;
  int ox = blockIdx.x * 16, oy = blockIdx.y * 16;
  int z16 = blockIdx.z * 16;
  float acc[4][4];
#pragma unroll
  for (int pp = 0; pp < 4; pp++)
#pragma unroll
    for (int i = 0; i < 4; i++) acc[pp][i] = 0.f;
  for (int cb = 0; cb < 64; cb += 16) {
    // stage input tile with inline x4 bilinear upsample (zero outside canvas)
    for (int i = t; i < 16 * 324; i += 256) {
      int ci = i / 324;
      int r = i - ci * 324;
      int iy = r / 18, ix = r - (r / 18) * 18;
      int gy = oy + iy - 1, gx = ox + ix - 1;
      float v = 0.f;
      if ((unsigned)gy < 256u && (unsigned)gx < 256u) {
        float sh = gy * 0.25f - 0.375f;
        float sw = gx * 0.25f - 0.375f;
        int h0 = (int)floorf(sh);
        float fh = sh - h0;
        int w0 = (int)floorf(sw);
        float fw = sw - w0;
        int h0c = max(h0, 0), h1c = min(h0 + 1, 63);
        int w0c = max(w0, 0), w1c = min(w0 + 1, 63);
        const float* xb = x + (size_t)(cb + ci) * 4096;
        v = (1.f - fh) * ((1.f - fw) * xb[h0c * 64 + w0c] + fw * xb[h0c * 64 + w1c]) +
            fh * ((1.f - fw) * xb[h1c * 64 + w0c] + fw * xb[h1c * 64 + w1c]);
      }
      xsh[ci][iy][ix] = v;
    }
    for (int i = t; i < 16 * 144; i += 256) {
      int ci = i / 144;
      int r = i - ci * 144;
      int col = r / 9, tap = r - (r / 9) * 9;
      wsh[ci][col][tap] = w[(size_t)(z16 + col) * 576 + (cb + ci) * 9 + tap];
    }
    __syncthreads();
#pragma unroll
    for (int ci = 0; ci < 16; ci++) {
      float xv[4][4];
#pragma unroll
      for (int r = 0; r < 4; r++) {
        float2 a = *(const float2*)&xsh[ci][2 * qy + r][2 * qx];
        float2 bq = *(const float2*)&xsh[ci][2 * qy + r][2 * qx + 2];
        xv[r][0] = a.x;
        xv[r][1] = a.y;
        xv[r][2] = bq.x;
        xv[r][3] = bq.y;
      }
#pragma unroll
      for (int i = 0; i < 4; i++) {
        int col = cog * 4 + i;
        float4 w0 = *(const float4*)&wsh[ci][col][0];
        float4 w1 = *(const float4*)&wsh[ci][col][4];
        float w8 = wsh[ci][col][8];
#pragma unroll
        for (int dy = 0; dy < 2; dy++)
#pragma unroll
          for (int dx = 0; dx < 2; dx++) {
            acc[dy * 2 + dx][i] += xv[dy + 0][dx + 0] * w0.x + xv[dy + 0][dx + 1] * w0.y +
                                   xv[dy + 0][dx + 2] * w0.z + xv[dy + 1][dx + 0] * w0.w +
                                   xv[dy + 1][dx + 1] * w1.x + xv[dy + 1][dx + 2] * w1.y +
                                   xv[dy + 2][dx + 0] * w1.z + xv[dy + 2][dx + 1] * w1.w +
                                   xv[dy + 2][dx + 2] * w8;
          }
      }
    }
    __syncthreads();
  }
#pragma unroll
  for (int dy = 0; dy < 2; dy++)
#pragma unroll
    for (int dx = 0; dx < 2; dx++) {
      int gy = oy + 2 * qy + dy, gx = ox + 2 * qx + dx;
#pragma unroll
      for (int i = 0; i < 4; i++) {
        int co = z16 + cog * 4 + i;
        float a = acc[dy * 2 + dx][i] + b[co];
        a = a / (1.f + __expf(-a));
        out[(size_t)co * 65536 + gy * 256 + gx] = a;
      }
    }
}

// ---------------- bilinear resize (half-pixel centers, edge clamp)
__global__ void k_resize(const float* __restrict__ x, float* __restrict__ out, int Hin,
                         int Win, int Hout, int Wout, float inv_scale) {
  int idx = blockIdx.x * blockDim.x + threadIdx.x;
  int HWo = Hout * Wout;
  if (idx >= 64 * HWo) return;
  int c = idx / HWo;
  int p = idx - c * HWo;
  int oh = p / Wout, ow = p - (p / Wout) * Wout;
  float sh = (oh + 0.5f) * inv_scale - 0.5f;
  float sw = (ow + 0.5f) * inv_scale - 0.5f;
  int h0 = (int)floorf(sh);
  float fh = sh - h0;
  int w0 = (int)floorf(sw);
  float fw = sw - w0;
  int h0c = min(max(h0, 0), Hin - 1), h1c = min(max(h0 + 1, 0), Hin - 1);
  int w0c = min(max(w0, 0), Win - 1), w1c = min(max(w0 + 1, 0), Win - 1);
  const float* xb = x + (size_t)c * Hin * Win;
  float v = (1.f - fh) * ((1.f - fw) * xb[h0c * Win + w0c] + fw * xb[h0c * Win + w1c]) +
            fh * ((1.f - fw) * xb[h1c * Win + w0c] + fw * xb[h1c * Win + w1c]);
  out[idx] = v;
}

extern "C" void kernel_launch(void* const* d_in, const int* in_sizes, int n_in, void* d_out,
                              int out_size, void* d_ws, size_t ws_size, hipStream_t stream) {
  const float* E0 = (const float*)d_in[0];
  const float* pe_w = (const float*)d_in[1];
  const float* pe_b = (const float*)d_in[2];
  const float* pe_lg = (const float*)d_in[3];
  const float* pe_lb = (const float*)d_in[4];
  const float* ln_g = (const float*)d_in[5];
  const float* ln_b = (const float*)d_in[6];
  const float* in_w = (const float*)d_in[7];
  const float* cv_w = (const float*)d_in[8];
  const float* cv_b = (const float*)d_in[9];
  const float* xp_w = (const float*)d_in[10];
  const float* dt_w = (const float*)d_in[11];
  const float* dt_b = (const float*)d_in[12];
  const float* A_log = (const float*)d_in[13];
  const float* Dp = (const float*)d_in[14];
  const float* on_g = (const float*)d_in[15];
  const float* on_b = (const float*)d_in[16];
  const float* out_pw = (const float*)d_in[17];
  const float* dn_w = (const float*)d_in[18];
  const float* dn_b = (const float*)d_in[19];
  const float* dn_g = (const float*)d_in[20];
  const float* dn_lb = (const float*)d_in[21];
  const float* up_w = (const float*)d_in[22];
  const float* up_b = (const float*)d_in[23];
  const float* oc_w = (const float*)d_in[24];
  const float* oc_b = (const float*)d_in[25];

  float* ws = (float*)d_ws;
  size_t off = 0;
  auto alloc = [&](size_t n) {
    float* p = ws + off;
    off += n;
    return p;
  };
  float* xA = alloc(64 * 4096);
  float* xB = alloc(64 * 4096);
  float* xc = alloc(128 * 4096);
  float* zb = alloc(128 * 4096);
  float* xcs = alloc(128 * 4096);
  float* dlt = alloc((size_t)4 * 128 * 4096);
  float* Bsb = alloc(4 * 16 * 4096);
  float* Csb = alloc(4 * 16 * 4096);
  float* ysb = alloc((size_t)4 * 128 * 4096);
  float* hloc = alloc((size_t)4 * 128 * 128 * 16);
  float* pAb = alloc((size_t)4 * 128 * 128 * 16);
  float* hin = alloc((size_t)4 * 128 * 128 * 16);
  float* sk0 = alloc(64 * 4096);
  float* sk1 = alloc(64 * 1024);
  float* sk2 = alloc(64 * 256);
  float* sk3 = alloc(64 * 64);
  float* tmpR = alloc((size_t)64 * 4096);

  k_patch_embed_ln<<<4096, 64, 0, stream>>>(E0, pe_w, pe_b, pe_lg, pe_lb, xB);
  float* x = xB;
  float* xalt = xA;

  int Hs[4] = {64, 32, 16, 8};
  int lgHs[4] = {6, 5, 4, 3};
  int CSs[4] = {32, 16, 8, 8};
  float* skips[4] = {sk0, sk1, sk2, sk3};
  int cur = 0;

  // runs dwconv..xproj..scan (split A/B/C); combine handled by caller
  auto vss_core = [&](int H, int lgH, int cs) {
    int L = H * H;
    int nc = L / cs;
    k_dwconv<<<(128 * L + 255) / 256, 256, 0, stream>>>(xc, cv_w + (size_t)cur * 128 * 9,
                                                        cv_b + cur * 128, xcs, H, lgH);
    dim3 gx(L, 4);
    k_xproj<<<gx, 256, 0, stream>>>(xcs, xp_w + (size_t)cur * 4 * 36 * 128,
                                    dt_w + (size_t)cur * 4 * 128 * 4, dt_b + cur * 4 * 128,
                                    dlt, Bsb, Csb, H, lgH);
    const float* Al = A_log + (size_t)cur * 4 * 128 * 16;
    const float* Dv = Dp + cur * 4 * 128;
    dim3 ga(nc, 4);
    k_scanA<<<ga, 128, 0, stream>>>(xcs, dlt, Bsb, Al, hloc, pAb, H, lgH, nc, cs);
    k_scanB<<<32, 256, 0, stream>>>(hloc, pAb, hin, nc);
    k_scanC<<<ga, 128, 0, stream>>>(xcs, dlt, Bsb, Csb, Al, Dv, hin, ysb, H, lgH, nc, cs);
  };

  for (int i = 0; i < 4; i++) {
    int H = Hs[i], lgH = lgHs[i];
    int L = H * H;
    // VSS block 1
    k_lnproj<<<L, 256, 0, stream>>>(x, ln_g + cur * 64, ln_b + cur * 64,
                                    in_w + (size_t)cur * 64 * 256, xc, zb, L);
    vss_core(H, lgH, CSs[i]);
    k_combine_lnproj<<<L, 256, 0, stream>>>(
        ysb, zb, x, on_g + cur * 128, on_b + cur * 128, out_pw + (size_t)cur * 128 * 64,
        ln_g + (cur + 1) * 64, ln_b + (cur + 1) * 64, in_w + (size_t)(cur + 1) * 64 * 256,
        xalt, xc, zb, H, lgH);
    std::swap(x, xalt);
    cur++;
    // VSS block 2 (xc/zb already produced)
    vss_core(H, lgH, CSs[i]);
    if (i < 3) {
      // write the stage output directly into the skip buffer (no memcpy)
      k_combine<<<L, 128, 0, stream>>>(ysb, zb, x, on_g + cur * 128, on_b + cur * 128,
                                       out_pw + (size_t)cur * 128 * 64, skips[i], H, lgH);
      cur++;
      int Ho = H / 2;
      k_conv_naive<<<(64 * Ho * Ho + 255) / 256, 256, 0, stream>>>(
          skips[i], dn_w + (size_t)i * 64 * 64 * 9, dn_b + i * 64, nullptr, xalt, H, Ho, 2, 0);
      k_ln2d64<<<Ho * Ho, 64, 0, stream>>>(xalt, dn_g + i * 64, dn_lb + i * 64, x, Ho * Ho);
    } else {
      k_combine<<<L, 128, 0, stream>>>(ysb, zb, x, on_g + cur * 128, on_b + cur * 128,
                                       out_pw + (size_t)cur * 128 * 64, xalt, H, lgH);
      std::swap(x, xalt);
      cur++;
    }
  }

  // up path: x at 8x8
  for (int i = 0; i < 3; i++) {
    int Hin = 8 << i, Ho = Hin * 2;
    k_resize<<<(64 * Ho * Ho + 255) / 256, 256, 0, stream>>>(x, tmpR, Hin, Hin, Ho, Ho, 0.5f);
    k_conv_naive<<<(64 * Ho * Ho + 255) / 256, 256, 0, stream>>>(
        tmpR, up_w + (size_t)i * 64 * 64 * 9, up_b + i * 64, skips[2 - i], xalt, Ho, Ho, 1, 1);
    std::swap(x, xalt);
  }

  // final: x at 64x64 -> fused (resize x4 + conv3x3 + silu) -> d_out
  dim3 gf(16, 16, 4);
  k_conv16_up<<<gf, 256, 0, stream>>>(x, oc_w, oc_b, (float*)d_out);
}

// Round 6
// 1229.617 us; speedup vs baseline: 1.2267x; 1.0999x over previous
//
#include <hip/hip_runtime.h>
#include <hip/hip_bf16.h>
#include <utility>

// ---------------- patch embed (conv4x4 s4) + ln2d64 fused; one wave per pixel
__global__ void k_patch_embed_ln(const float* __restrict__ E0, const float* __restrict__ w,
                                 const float* __restrict__ b, const float* __restrict__ g,
                                 const float* __restrict__ lb, float* __restrict__ out) {
  int p = blockIdx.x;
  int c = threadIdx.x;  // 64
  int oh = p >> 6, ow = p & 63;
  const float* src = E0 + (oh * 4) * 256 + ow * 4;
  const float* wc = w + c * 16;
  float acc = b[c];
#pragma unroll
  for (int i = 0; i < 4; i++)
#pragma unroll
    for (int j = 0; j < 4; j++) acc += src[i * 256 + j] * wc[i * 4 + j];
  float s = acc, s2 = acc * acc;
#pragma unroll
  for (int m = 32; m >= 1; m >>= 1) {
    s += __shfl_xor(s, m, 64);
    s2 += __shfl_xor(s2, m, 64);
  }
  float mu = s * (1.f / 64.f);
  float var = s2 * (1.f / 64.f) - mu * mu;
  float rstd = rsqrtf(var + 1e-6f);
  out[c * 4096 + p] = (acc - mu) * rstd * g[c] + lb[c];
}

// ---------------- ln2d over C=64 channels (one wave per pixel)
__global__ void k_ln2d64(const float* __restrict__ x, const float* __restrict__ g,
                         const float* __restrict__ b, float* __restrict__ y, int HW) {
  int p = blockIdx.x;
  int c = threadIdx.x;
  float v = x[c * HW + p];
  float s = v, s2 = v * v;
#pragma unroll
  for (int m = 32; m >= 1; m >>= 1) {
    s += __shfl_xor(s, m, 64);
    s2 += __shfl_xor(s2, m, 64);
  }
  float mu = s * (1.f / 64.f);
  float var = s2 * (1.f / 64.f) - mu * mu;
  float rstd = rsqrtf(var + 1e-6f);
  y[c * HW + p] = (v - mu) * rstd * g[c] + b[c];
}

// ---------------- fused ln2d(C=64) + input projection (64 -> 256), split xc/z
__global__ void k_lnproj(const float* __restrict__ x, const float* __restrict__ g,
                         const float* __restrict__ b, const float* __restrict__ w,
                         float* __restrict__ xc, float* __restrict__ z, int HW) {
  int p = blockIdx.x;
  int t = threadIdx.x;  // 256 threads
  __shared__ float hsh[64];
  if (t < 64) {
    float v = x[t * HW + p];
    float s = v, s2 = v * v;
#pragma unroll
    for (int m = 32; m >= 1; m >>= 1) {
      s += __shfl_xor(s, m, 64);
      s2 += __shfl_xor(s2, m, 64);
    }
    float mu = s * (1.f / 64.f);
    float var = s2 * (1.f / 64.f) - mu * mu;
    float rstd = rsqrtf(var + 1e-6f);
    hsh[t] = (v - mu) * rstd * g[t] + b[t];
  }
  __syncthreads();
  float acc = 0.f;
  const float* wp = w + t;  // w[c*256 + t]
#pragma unroll
  for (int c = 0; c < 64; c++) acc += hsh[c] * wp[c * 256];
  if (t < 128)
    xc[(size_t)p * 128 + t] = acc;
  else
    z[(size_t)p * 128 + (t - 128)] = acc;
}

// ---------------- depthwise conv 3x3 pad 1 + silu; pixel-major [L][128]
__global__ void k_dwconv(const float* __restrict__ xc, const float* __restrict__ w,
                         const float* __restrict__ b, float* __restrict__ out, int H, int lgH) {
  int HW = H * H;
  int idx = blockIdx.x * blockDim.x + threadIdx.x;
  if (idx >= 128 * HW) return;
  int p = idx >> 7;
  int d = idx & 127;
  int ph = p >> lgH, pw = p & (H - 1);
  const float* wp = w + d * 9;
  float acc = b[d];
#pragma unroll
  for (int i = 0; i < 3; i++) {
    int ih = ph + i - 1;
    if (ih < 0 || ih >= H) continue;
#pragma unroll
    for (int j = 0; j < 3; j++) {
      int iw = pw + j - 1;
      if (iw < 0 || iw >= H) continue;
      acc += xc[(size_t)(ih * H + iw) * 128 + d] * wp[i * 3 + j];
    }
  }
  out[(size_t)p * 128 + d] = acc / (1.f + __expf(-acc));
}

// ---------------- fused x-projection (+softplus delta) + scanA
// block = (chunk c, dir k); weights in registers across cs l's; scanA from LDS
__global__ void __launch_bounds__(256) k_xproj_scanA(
    const float* __restrict__ xcs, const float* __restrict__ xpw,
    const float* __restrict__ dtw, const float* __restrict__ dtb,
    const float* __restrict__ A_log, float* __restrict__ delta, float* __restrict__ Bs,
    float* __restrict__ Cs, float* __restrict__ hloc, float* __restrict__ pA, int H,
    int lgH, int nc, int cs) {
  int L = H * H;
  int c = blockIdx.x;
  int k = blockIdx.y;
  int t = threadIdx.x;
  int l0 = c * cs;
  __shared__ float xs[32][128];
  __shared__ float dsh[32][128];
  __shared__ float Bsh[32][16];
  __shared__ float r4s[4];
  // stage xs (u at permuted positions) for all cs l's
  for (int i = t; i < cs * 128; i += 256) {
    int j = i >> 7, d = i & 127;
    int l = l0 + j;
    int lm = (k & 2) ? (L - 1 - l) : l;
    int idx = (k & 1) ? ((lm & (H - 1)) * H + (lm >> lgH)) : lm;
    xs[j][d] = xcs[(size_t)idx * 128 + d];
  }
  // per-thread weight chunk in registers
  int r = t >> 2, q = t & 3;
  float4 wreg[8];
  if (t < 144) {
    const float4* wp = (const float4*)(xpw + (size_t)(k * 36 + r) * 128 + q * 32);
#pragma unroll
    for (int m = 0; m < 8; m++) wreg[m] = wp[m];
  }
  float4 dtw4 = {0, 0, 0, 0};
  float dtbv = 0.f;
  if (t < 128) {
    dtw4 = *(const float4*)(dtw + (size_t)(k * 128 + t) * 4);
    dtbv = dtb[k * 128 + t];
  }
  __syncthreads();
  for (int j = 0; j < cs; j++) {
    if (t < 144) {
      const float4* xp = (const float4*)&xs[j][q * 32];
      float a = 0.f;
#pragma unroll
      for (int m = 0; m < 8; m++) {
        float4 xv = xp[m];
        a += xv.x * wreg[m].x + xv.y * wreg[m].y + xv.z * wreg[m].z + xv.w * wreg[m].w;
      }
      a += __shfl_xor(a, 1);
      a += __shfl_xor(a, 2);
      if (q == 0) {
        int l = l0 + j;
        if (r < 4)
          r4s[r] = a;
        else if (r < 20) {
          Bsh[j][r - 4] = a;
          Bs[((size_t)k * L + l) * 16 + (r - 4)] = a;
        } else
          Cs[((size_t)k * L + l) * 16 + (r - 20)] = a;
      }
    }
    __syncthreads();
    if (t < 128) {
      float dt = dtbv + r4s[0] * dtw4.x + r4s[1] * dtw4.y + r4s[2] * dtw4.z + r4s[3] * dtw4.w;
      float sp = fmaxf(dt, 0.f) + log1pf(__expf(-fabsf(dt)));
      dsh[j][t] = sp;
      delta[((size_t)k * L + (l0 + j)) * 128 + t] = sp;
    }
    __syncthreads();
  }
  // phase 2: scanA entirely from LDS
  if (t < 128) {
    int d = t;
    float A[16], h[16];
#pragma unroll
    for (int n = 0; n < 16; n++) {
      A[n] = -__expf(A_log[(size_t)(k * 128 + d) * 16 + n]);
      h[n] = 0.f;
    }
    float sumdt = 0.f;
    for (int j = 0; j < cs; j++) {
      float u = xs[j][d];
      float dt = dsh[j][d];
      float du = dt * u;
      sumdt += dt;
      const float4* bp = (const float4*)Bsh[j];
      float4 B0 = bp[0], B1 = bp[1], B2 = bp[2], B3 = bp[3];
      float Bv[16] = {B0.x, B0.y, B0.z, B0.w, B1.x, B1.y, B1.z, B1.w,
                      B2.x, B2.y, B2.z, B2.w, B3.x, B3.y, B3.z, B3.w};
#pragma unroll
      for (int n = 0; n < 16; n++) h[n] = __expf(dt * A[n]) * h[n] + Bv[n] * du;
    }
    size_t base = (((size_t)(k * 128 + d)) * nc + c) * 16;
#pragma unroll
    for (int n = 0; n < 16; n++) {
      hloc[base + n] = h[n];
      pA[base + n] = __expf(A[n] * sumdt);
    }
  }
}

// ---------------- scan phase B: 8192 independent (k,d,n) recurrences
__global__ void k_scanB(const float* __restrict__ hloc, const float* __restrict__ pA,
                        float* __restrict__ hinit, int nc) {
  int tid = blockIdx.x * blockDim.x + threadIdx.x;  // 8192 total
  int k = tid >> 11;
  int d = (tid >> 4) & 127;
  int n = tid & 15;
  size_t rb = ((size_t)(k * 128 + d)) * nc * 16 + n;
  float h = 0.f;
  for (int c = 0; c < nc; c++) {
    size_t a = rb + (size_t)c * 16;
    hinit[a] = h;
    h = pA[a] * h + hloc[a];
  }
}

// ---------------- scan phase C: rescan with correct init, emit y; ys: [k][L][128]
__global__ void k_scanC(const float* __restrict__ xcs, const float* __restrict__ delta,
                        const float* __restrict__ Bs, const float* __restrict__ Cs,
                        const float* __restrict__ A_log, const float* __restrict__ Dp,
                        const float* __restrict__ hinit, float* __restrict__ ys, int H,
                        int lgH, int nc, int cs) {
  int L = H * H;
  int c = blockIdx.x;
  int k = blockIdx.y;
  int d = threadIdx.x;
  float A[16], h[16];
  size_t base = (((size_t)(k * 128 + d)) * nc + c) * 16;
#pragma unroll
  for (int n = 0; n < 16; n++) {
    A[n] = -__expf(A_log[(size_t)(k * 128 + d) * 16 + n]);
    h[n] = hinit[base + n];
  }
  float Dv = Dp[k * 128 + d];
  int l0 = c * cs;
  for (int l = l0; l < l0 + cs; l++) {
    int lm = (k & 2) ? (L - 1 - l) : l;
    int idx = (k & 1) ? ((lm & (H - 1)) * H + (lm >> lgH)) : lm;
    float u = xcs[(size_t)idx * 128 + d];
    float dt = delta[((size_t)k * L + l) * 128 + d];
    float du = dt * u;
    const float4* bp = (const float4*)(Bs + ((size_t)k * L + l) * 16);
    float4 B0 = bp[0], B1 = bp[1], B2 = bp[2], B3 = bp[3];
    float Bv[16] = {B0.x, B0.y, B0.z, B0.w, B1.x, B1.y, B1.z, B1.w,
                    B2.x, B2.y, B2.z, B2.w, B3.x, B3.y, B3.z, B3.w};
    const float4* cp = (const float4*)(Cs + ((size_t)k * L + l) * 16);
    float4 C0 = cp[0], C1 = cp[1], C2 = cp[2], C3 = cp[3];
    float Cv[16] = {C0.x, C0.y, C0.z, C0.w, C1.x, C1.y, C1.z, C1.w,
                    C2.x, C2.y, C2.z, C2.w, C3.x, C3.y, C3.z, C3.w};
    float y = 0.f;
#pragma unroll
    for (int n = 0; n < 16; n++) {
      h[n] = __expf(dt * A[n]) * h[n] + Bv[n] * du;
      y += h[n] * Cv[n];
    }
    ys[((size_t)k * L + l) * 128 + d] = y + Dv * u;
  }
}

// ---------------- combine (plain): 4 dirs + LN128 + gate + out proj + residual
__global__ void k_combine(const float* __restrict__ ys, const float* __restrict__ z,
                          const float* __restrict__ xin, const float* __restrict__ ong,
                          const float* __restrict__ onb, const float* __restrict__ outw,
                          float* __restrict__ xout, int H, int lgH) {
  int L = H * H;
  int p = blockIdx.x;
  int d = threadIdx.x;  // 128
  int ph = p >> lgH, pw = p & (H - 1);
  int l1 = pw * H + ph;
  float yv = ys[((size_t)0 * L + p) * 128 + d] + ys[((size_t)1 * L + l1) * 128 + d] +
             ys[((size_t)2 * L + (L - 1 - p)) * 128 + d] +
             ys[((size_t)3 * L + (L - 1 - l1)) * 128 + d];
  float s = yv, s2 = yv * yv;
#pragma unroll
  for (int m = 32; m >= 1; m >>= 1) {
    s += __shfl_xor(s, m, 64);
    s2 += __shfl_xor(s2, m, 64);
  }
  __shared__ float ws1[2], ws2[2];
  int wid = d >> 6;
  if ((d & 63) == 0) {
    ws1[wid] = s;
    ws2[wid] = s2;
  }
  __syncthreads();
  float tot = ws1[0] + ws1[1], tot2 = ws2[0] + ws2[1];
  float mu = tot * (1.f / 128.f);
  float var = tot2 * (1.f / 128.f) - mu * mu;
  float rstd = rsqrtf(var + 1e-6f);
  float zt = z[(size_t)p * 128 + d];
  float yt = ((yv - mu) * rstd * ong[d] + onb[d]) * (zt / (1.f + __expf(-zt)));
  __shared__ float ysm[128];
  ysm[d] = yt;
  __syncthreads();
  if (d < 64) {
    float acc = xin[(size_t)d * L + p];
#pragma unroll
    for (int q = 0; q < 128; q++) acc += ysm[q] * outw[q * 64 + d];
    xout[(size_t)d * L + p] = acc;
  }
}

// ---------------- combine + next-block LN64 + in-proj fused (256 threads/pixel)
__global__ void k_combine_lnproj(const float* __restrict__ ys, const float* __restrict__ z,
                                 const float* __restrict__ xin, const float* __restrict__ ong,
                                 const float* __restrict__ onb, const float* __restrict__ outw,
                                 const float* __restrict__ g2, const float* __restrict__ b2,
                                 const float* __restrict__ w2, float* __restrict__ xout,
                                 float* __restrict__ xc, float* __restrict__ zout, int H,
                                 int lgH) {
  int L = H * H;
  int p = blockIdx.x;
  int t = threadIdx.x;  // 256
  __shared__ float ysm[128], hnsh[64];
  __shared__ float ws1[2], ws2[2];
  float yv = 0.f;
  if (t < 128) {
    int ph = p >> lgH, pw = p & (H - 1);
    int l1 = pw * H + ph;
    yv = ys[((size_t)0 * L + p) * 128 + t] + ys[((size_t)1 * L + l1) * 128 + t] +
         ys[((size_t)2 * L + (L - 1 - p)) * 128 + t] +
         ys[((size_t)3 * L + (L - 1 - l1)) * 128 + t];
    float s = yv, s2 = yv * yv;
#pragma unroll
    for (int m = 32; m >= 1; m >>= 1) {
      s += __shfl_xor(s, m, 64);
      s2 += __shfl_xor(s2, m, 64);
    }
    if ((t & 63) == 0) {
      ws1[t >> 6] = s;
      ws2[t >> 6] = s2;
    }
  }
  __syncthreads();
  if (t < 128) {
    float tot = ws1[0] + ws1[1], tot2 = ws2[0] + ws2[1];
    float mu = tot * (1.f / 128.f);
    float var = tot2 * (1.f / 128.f) - mu * mu;
    float rstd = rsqrtf(var + 1e-6f);
    float zt = z[(size_t)p * 128 + t];
    ysm[t] = ((yv - mu) * rstd * ong[t] + onb[t]) * (zt / (1.f + __expf(-zt)));
  }
  __syncthreads();
  if (t < 64) {
    float acc = xin[(size_t)t * L + p];
#pragma unroll
    for (int q = 0; q < 128; q++) acc += ysm[q] * outw[q * 64 + t];
    xout[(size_t)t * L + p] = acc;  // residual x for next combine
    float s = acc, s2 = acc * acc;
#pragma unroll
    for (int m = 32; m >= 1; m >>= 1) {
      s += __shfl_xor(s, m, 64);
      s2 += __shfl_xor(s2, m, 64);
    }
    float mu = s * (1.f / 64.f);
    float var = s2 * (1.f / 64.f) - mu * mu;
    float rstd = rsqrtf(var + 1e-6f);
    hnsh[t] = (acc - mu) * rstd * g2[t] + b2[t];
  }
  __syncthreads();
  float a2 = 0.f;
  const float* wp = w2 + t;
#pragma unroll
  for (int c = 0; c < 64; c++) a2 += hnsh[c] * wp[c * 256];
  if (t < 128)
    xc[(size_t)p * 128 + t] = a2;
  else
    zout[(size_t)p * 128 + (t - 128)] = a2;
}

// ---------------- naive per-output conv3x3 64->64 (stride 1 or 2, silu, skip)
__global__ void k_conv_naive(const float* __restrict__ x, const float* __restrict__ w,
                             const float* __restrict__ b, const float* __restrict__ skip,
                             float* __restrict__ out, int Hin, int Hout, int stride,
                             int do_silu) {
  int idx = blockIdx.x * blockDim.x + threadIdx.x;
  int HWo = Hout * Hout;
  if (idx >= 64 * HWo) return;
  int co = idx / HWo;
  int p = idx - co * HWo;
  int oh = p / Hout, ow = p - (p / Hout) * Hout;
  float acc = b[co];
  const float* wb = w + co * 64 * 9;
  for (int ci = 0; ci < 64; ci++) {
    const float* xb = x + (size_t)ci * Hin * Hin;
    const float* wc = wb + ci * 9;
#pragma unroll
    for (int i = 0; i < 3; i++) {
      int ih = oh * stride + i - 1;
      if (ih < 0 || ih >= Hin) continue;
#pragma unroll
      for (int j = 0; j < 3; j++) {
        int iw = ow * stride + j - 1;
        if (iw < 0 || iw >= Hin) continue;
        acc += xb[ih * Hin + iw] * wc[i * 3 + j];
      }
    }
  }
  if (do_silu) acc = acc / (1.f + __expf(-acc));
  if (skip) acc += skip[idx];
  out[idx] = acc;
}

// ---------------- final: fused (x4 bilinear resize) + conv3x3 + silu
// grid (16,16,2): 16x16 px tile, 32 co/block. 256 thr: 2x2 px x 8 co.
// Source 6x6 patch + lerp params staged ONCE; per-chunk xsh is LDS->LDS.
__global__ void __launch_bounds__(256) k_conv16_up(const float* __restrict__ x,
                                                   const float* __restrict__ w,
                                                   const float* __restrict__ b,
                                                   float* __restrict__ out) {
  __shared__ float ssh[64][36];
  __shared__ float pfh[324], pfw[324];
  __shared__ int poff[324];
  __shared__ __align__(16) float xsh[8][18][20];
  __shared__ __align__(16) float wsh[8][32][12];
  int t = threadIdx.x;
  int q = t & 63, cog = t >> 6;
  int qx = q & 7, qy = q >> 3;
  int ox = blockIdx.x * 16, oy = blockIdx.y * 16;
  int z32 = blockIdx.z * 32;
  int sy0 = (oy >> 2) - 1, sx0 = (ox >> 2) - 1;
  // stage clamped 6x6 source patch for all 64 ci
  for (int i = t; i < 64 * 36; i += 256) {
    int ci = i / 36;
    int rr = i - ci * 36;
    int ry = rr / 6, cc = rr - ry * 6;
    int sy = min(max(sy0 + ry, 0), 63);
    int sx = min(max(sx0 + cc, 0), 63);
    ssh[ci][rr] = x[(size_t)ci * 4096 + sy * 64 + sx];
  }
  // stage lerp params for the 18x18 upsampled tile (+halo)
  for (int i = t; i < 324; i += 256) {
    int iy = i / 18, ix = i - iy * 18;
    int gy = oy + iy - 1, gx = ox + ix - 1;
    if ((unsigned)gy < 256u && (unsigned)gx < 256u) {
      float sh = gy * 0.25f - 0.375f;
      float sw = gx * 0.25f - 0.375f;
      int h0 = (int)floorf(sh), w0 = (int)floorf(sw);
      pfh[i] = sh - h0;
      pfw[i] = sw - w0;
      poff[i] = (h0 - sy0) * 6 + (w0 - sx0);
    } else {
      poff[i] = -1;
      pfh[i] = 0.f;
      pfw[i] = 0.f;
    }
  }
  float acc[4][8];
#pragma unroll
  for (int pp = 0; pp < 4; pp++)
#pragma unroll
    for (int i = 0; i < 8; i++) acc[pp][i] = 0.f;
  __syncthreads();
  for (int cb = 0; cb < 64; cb += 8) {
    // xsh from ssh via lerp (LDS->LDS, no global latency)
    for (int i = t; i < 8 * 324; i += 256) {
      int ci = i / 324;
      int rdx = i - ci * 324;
      int off = poff[rdx];
      float v = 0.f;
      if (off >= 0) {
        float fh = pfh[rdx], fw = pfw[rdx];
        const float* s = &ssh[cb + ci][off];
        v = (1.f - fh) * ((1.f - fw) * s[0] + fw * s[1]) +
            fh * ((1.f - fw) * s[6] + fw * s[7]);
      }
      int iy = rdx / 18;
      xsh[ci][iy][rdx - iy * 18] = v;
    }
    for (int i = t; i < 8 * 288; i += 256) {
      int ci = i / 288;
      int rr = i - ci * 288;
      int col = rr / 9, tap = rr - col * 9;
      wsh[ci][col][tap] = w[(size_t)(z32 + col) * 576 + (cb + ci) * 9 + tap];
    }
    __syncthreads();
#pragma unroll
    for (int ci = 0; ci < 8; ci++) {
      float xv[4][4];
#pragma unroll
      for (int r = 0; r < 4; r++) {
        float2 a = *(const float2*)&xsh[ci][2 * qy + r][2 * qx];
        float2 bq = *(const float2*)&xsh[ci][2 * qy + r][2 * qx + 2];
        xv[r][0] = a.x;
        xv[r][1] = a.y;
        xv[r][2] = bq.x;
        xv[r][3] = bq.y;
      }
#pragma unroll
      for (int i = 0; i < 8; i++) {
        int col = cog * 8 + i;
        float4 w0v = *(const float4*)&wsh[ci][col][0];
        float4 w1v = *(const float4*)&wsh[ci][col][4];
        float w8v = wsh[ci][col][8];
#pragma unroll
        for (int dy = 0; dy < 2; dy++)
#pragma unroll
          for (int dx = 0; dx < 2; dx++) {
            acc[dy * 2 + dx][i] += xv[dy + 0][dx + 0] * w0v.x + xv[dy + 0][dx + 1] * w0v.y +
                                   xv[dy + 0][dx + 2] * w0v.z + xv[dy + 1][dx + 0] * w0v.w +
                                   xv[dy + 1][dx + 1] * w1v.x + xv[dy + 1][dx + 2] * w1v.y +
                                   xv[dy + 2][dx + 0] * w1v.z + xv[dy + 2][dx + 1] * w1v.w +
                                   xv[dy + 2][dx + 2] * w8v;
          }
      }
    }
    __syncthreads();
  }
#pragma unroll
  for (int dy = 0; dy < 2; dy++)
#pragma unroll
    for (int dx = 0; dx < 2; dx++) {
      int gy = oy + 2 * qy + dy, gx = ox + 2 * qx + dx;
#pragma unroll
      for (int i = 0; i < 8; i++) {
        int co = z32 + cog * 8 + i;
        float a = acc[dy * 2 + dx][i] + b[co];
        a = a / (1.f + __expf(-a));
        out[(size_t)co * 65536 + gy * 256 + gx] = a;
      }
    }
}

// ---------------- bilinear resize (half-pixel centers, edge clamp)
__global__ void k_resize(const float* __restrict__ x, float* __restrict__ out, int Hin,
                         int Win, int Hout, int Wout, float inv_scale) {
  int idx = blockIdx.x * blockDim.x + threadIdx.x;
  int HWo = Hout * Wout;
  if (idx >= 64 * HWo) return;
  int c = idx / HWo;
  int p = idx - c * HWo;
  int oh = p / Wout, ow = p - (p / Wout) * Wout;
  float sh = (oh + 0.5f) * inv_scale - 0.5f;
  float sw = (ow + 0.5f) * inv_scale - 0.5f;
  int h0 = (int)floorf(sh);
  float fh = sh - h0;
  int w0 = (int)floorf(sw);
  float fw = sw - w0;
  int h0c = min(max(h0, 0), Hin - 1), h1c = min(max(h0 + 1, 0), Hin - 1);
  int w0c = min(max(w0, 0), Win - 1), w1c = min(max(w0 + 1, 0), Win - 1);
  const float* xb = x + (size_t)c * Hin * Win;
  float v = (1.f - fh) * ((1.f - fw) * xb[h0c * Win + w0c] + fw * xb[h0c * Win + w1c]) +
            fh * ((1.f - fw) * xb[h1c * Win + w0c] + fw * xb[h1c * Win + w1c]);
  out[idx] = v;
}

extern "C" void kernel_launch(void* const* d_in, const int* in_sizes, int n_in, void* d_out,
                              int out_size, void* d_ws, size_t ws_size, hipStream_t stream) {
  const float* E0 = (const float*)d_in[0];
  const float* pe_w = (const float*)d_in[1];
  const float* pe_b = (const float*)d_in[2];
  const float* pe_lg = (const float*)d_in[3];
  const float* pe_lb = (const float*)d_in[4];
  const float* ln_g = (const float*)d_in[5];
  const float* ln_b = (const float*)d_in[6];
  const float* in_w = (const float*)d_in[7];
  const float* cv_w = (const float*)d_in[8];
  const float* cv_b = (const float*)d_in[9];
  const float* xp_w = (const float*)d_in[10];
  const float* dt_w = (const float*)d_in[11];
  const float* dt_b = (const float*)d_in[12];
  const float* A_log = (const float*)d_in[13];
  const float* Dp = (const float*)d_in[14];
  const float* on_g = (const float*)d_in[15];
  const float* on_b = (const float*)d_in[16];
  const float* out_pw = (const float*)d_in[17];
  const float* dn_w = (const float*)d_in[18];
  const float* dn_b = (const float*)d_in[19];
  const float* dn_g = (const float*)d_in[20];
  const float* dn_lb = (const float*)d_in[21];
  const float* up_w = (const float*)d_in[22];
  const float* up_b = (const float*)d_in[23];
  const float* oc_w = (const float*)d_in[24];
  const float* oc_b = (const float*)d_in[25];

  float* ws = (float*)d_ws;
  size_t off = 0;
  auto alloc = [&](size_t n) {
    float* p = ws + off;
    off += n;
    return p;
  };
  float* xA = alloc(64 * 4096);
  float* xB = alloc(64 * 4096);
  float* xc = alloc(128 * 4096);
  float* zb = alloc(128 * 4096);
  float* xcs = alloc(128 * 4096);
  float* dlt = alloc((size_t)4 * 128 * 4096);
  float* Bsb = alloc(4 * 16 * 4096);
  float* Csb = alloc(4 * 16 * 4096);
  float* ysb = alloc((size_t)4 * 128 * 4096);
  float* hloc = alloc((size_t)4 * 128 * 128 * 16);
  float* pAb = alloc((size_t)4 * 128 * 128 * 16);
  float* hin = alloc((size_t)4 * 128 * 128 * 16);
  float* sk0 = alloc(64 * 4096);
  float* sk1 = alloc(64 * 1024);
  float* sk2 = alloc(64 * 256);
  float* sk3 = alloc(64 * 64);
  float* tmpR = alloc((size_t)64 * 4096);

  k_patch_embed_ln<<<4096, 64, 0, stream>>>(E0, pe_w, pe_b, pe_lg, pe_lb, xB);
  float* x = xB;
  float* xalt = xA;

  int Hs[4] = {64, 32, 16, 8};
  int lgHs[4] = {6, 5, 4, 3};
  int CSs[4] = {32, 16, 8, 8};
  float* skips[4] = {sk0, sk1, sk2, sk3};
  int cur = 0;

  // dwconv -> fused xproj+scanA -> scanB -> scanC
  auto vss_core = [&](int H, int lgH, int cs) {
    int L = H * H;
    int nc = L / cs;
    k_dwconv<<<(128 * L + 255) / 256, 256, 0, stream>>>(xc, cv_w + (size_t)cur * 128 * 9,
                                                        cv_b + cur * 128, xcs, H, lgH);
    const float* Al = A_log + (size_t)cur * 4 * 128 * 16;
    const float* Dv = Dp + cur * 4 * 128;
    dim3 ga(nc, 4);
    k_xproj_scanA<<<ga, 256, 0, stream>>>(xcs, xp_w + (size_t)cur * 4 * 36 * 128,
                                          dt_w + (size_t)cur * 4 * 128 * 4,
                                          dt_b + cur * 4 * 128, Al, dlt, Bsb, Csb, hloc,
                                          pAb, H, lgH, nc, cs);
    k_scanB<<<32, 256, 0, stream>>>(hloc, pAb, hin, nc);
    dim3 gc(nc, 4);
    k_scanC<<<gc, 128, 0, stream>>>(xcs, dlt, Bsb, Csb, Al, Dv, hin, ysb, H, lgH, nc, cs);
  };

  for (int i = 0; i < 4; i++) {
    int H = Hs[i], lgH = lgHs[i];
    int L = H * H;
    // VSS block 1
    k_lnproj<<<L, 256, 0, stream>>>(x, ln_g + cur * 64, ln_b + cur * 64,
                                    in_w + (size_t)cur * 64 * 256, xc, zb, L);
    vss_core(H, lgH, CSs[i]);
    k_combine_lnproj<<<L, 256, 0, stream>>>(
        ysb, zb, x, on_g + cur * 128, on_b + cur * 128, out_pw + (size_t)cur * 128 * 64,
        ln_g + (cur + 1) * 64, ln_b + (cur + 1) * 64, in_w + (size_t)(cur + 1) * 64 * 256,
        xalt, xc, zb, H, lgH);
    std::swap(x, xalt);
    cur++;
    // VSS block 2 (xc/zb already produced)
    vss_core(H, lgH, CSs[i]);
    if (i < 3) {
      k_combine<<<L, 128, 0, stream>>>(ysb, zb, x, on_g + cur * 128, on_b + cur * 128,
                                       out_pw + (size_t)cur * 128 * 64, skips[i], H, lgH);
      cur++;
      int Ho = H / 2;
      k_conv_naive<<<(64 * Ho * Ho + 255) / 256, 256, 0, stream>>>(
          skips[i], dn_w + (size_t)i * 64 * 64 * 9, dn_b + i * 64, nullptr, xalt, H, Ho, 2, 0);
      k_ln2d64<<<Ho * Ho, 64, 0, stream>>>(xalt, dn_g + i * 64, dn_lb + i * 64, x, Ho * Ho);
    } else {
      k_combine<<<L, 128, 0, stream>>>(ysb, zb, x, on_g + cur * 128, on_b + cur * 128,
                                       out_pw + (size_t)cur * 128 * 64, xalt, H, lgH);
      std::swap(x, xalt);
      cur++;
    }
  }

  // up path: x at 8x8
  for (int i = 0; i < 3; i++) {
    int Hin = 8 << i, Ho = Hin * 2;
    k_resize<<<(64 * Ho * Ho + 255) / 256, 256, 0, stream>>>(x, tmpR, Hin, Hin, Ho, Ho, 0.5f);
    k_conv_naive<<<(64 * Ho * Ho + 255) / 256, 256, 0, stream>>>(
        tmpR, up_w + (size_t)i * 64 * 64 * 9, up_b + i * 64, skips[2 - i], xalt, Ho, Ho, 1, 1);
    std::swap(x, xalt);
  }

  // final: x at 64x64 -> fused (resize x4 + conv3x3 + silu) -> d_out
  dim3 gf(16, 16, 2);
  k_conv16_up<<<gf, 256, 0, stream>>>(x, oc_w, oc_b, (float*)d_out);
}